// Round 3
// baseline (143.477 us; speedup 1.0000x reference)
//
#include <hip/hip_runtime.h>

// score[e] = dot(h[src[e]], h[dst[e]]), D=128 f32, E=600k, N=100k.
// Strategy: counting-sort edges by src, then one 32-lane group per NODE:
// load h[src] into registers once, loop over that node's dst list.
// Halves gather demand (614 -> ~365 MB) vs edge-parallel.
//
// Pipeline (all on stream): memset cnt/cur -> histogram -> 3-kernel scan
// -> scatter (sorted_dst, sorted_eid) -> node-parallel dot kernel.
// Output values are order-independent -> deterministic despite atomics.

#define SCAN_B 1024

__device__ __forceinline__ float dot_reduce32(float4 a, float4 b) {
    float v = a.x * b.x + a.y * b.y + a.z * b.z + a.w * b.w;
    v += __shfl_xor(v, 16);
    v += __shfl_xor(v, 8);
    v += __shfl_xor(v, 4);
    v += __shfl_xor(v, 2);
    v += __shfl_xor(v, 1);
    return v;
}

__global__ void k_hist(const int* __restrict__ src, unsigned* __restrict__ cnt, int E) {
    int e = blockIdx.x * blockDim.x + threadIdx.x;
    if (e < E) atomicAdd(&cnt[src[e]], 1u);
}

// Exclusive scan per block of SCAN_B; optional per-block totals to part[].
__global__ void k_scan_block(const unsigned* __restrict__ in, unsigned* __restrict__ outx,
                             unsigned* __restrict__ part, int n) {
    __shared__ unsigned tmp[SCAN_B];
    int i = blockIdx.x * SCAN_B + threadIdx.x;
    unsigned x = (i < n) ? in[i] : 0u;
    tmp[threadIdx.x] = x;
    __syncthreads();
    for (int ofs = 1; ofs < SCAN_B; ofs <<= 1) {
        unsigned t = (threadIdx.x >= (unsigned)ofs) ? tmp[threadIdx.x - ofs] : 0u;
        __syncthreads();
        tmp[threadIdx.x] += t;
        __syncthreads();
    }
    if (i < n) outx[i] = tmp[threadIdx.x] - x;  // exclusive
    if (part && threadIdx.x == SCAN_B - 1) part[blockIdx.x] = tmp[SCAN_B - 1];
}

__global__ void k_scan_add(unsigned* __restrict__ outx, const unsigned* __restrict__ part, int n) {
    int i = blockIdx.x * SCAN_B + threadIdx.x;
    if (i < n) outx[i] += part[blockIdx.x];
}

__global__ void k_scatter(const int* __restrict__ src, const int* __restrict__ dst,
                          const unsigned* __restrict__ off, unsigned* __restrict__ cur,
                          unsigned* __restrict__ sdst, unsigned* __restrict__ seid, int E) {
    int e = blockIdx.x * blockDim.x + threadIdx.x;
    if (e >= E) return;
    int s = src[e];
    unsigned pos = off[s] + atomicAdd(&cur[s], 1u);
    sdst[pos] = (unsigned)dst[e];
    seid[pos] = (unsigned)e;
}

// One 32-lane group per node: src row in registers, loop over dst list.
__global__ void k_node_dot(const float* __restrict__ h,
                           const unsigned* __restrict__ off,
                           const unsigned* __restrict__ sdst,
                           const unsigned* __restrict__ seid,
                           float* __restrict__ out, int N, int E) {
    const int lane = threadIdx.x & 31;
    int node = (int)(((long long)blockIdx.x * blockDim.x + threadIdx.x) >> 5);
    if (node >= N) return;

    const float4* __restrict__ H = reinterpret_cast<const float4*>(h);
    float4 a = H[(size_t)node * 32 + lane];

    int beg = (int)off[node];
    int end = (node + 1 < N) ? (int)off[node + 1] : E;

    int e = beg;
    for (; e + 1 < end; e += 2) {
        unsigned d0 = sdst[e], d1 = sdst[e + 1];
        float4 b0 = H[(size_t)d0 * 32 + lane];
        float4 b1 = H[(size_t)d1 * 32 + lane];
        float v0 = dot_reduce32(a, b0);
        float v1 = dot_reduce32(a, b1);
        if (lane == 0) {
            out[seid[e]]     = v0;
            out[seid[e + 1]] = v1;
        }
    }
    if (e < end) {
        unsigned d0 = sdst[e];
        float4 b0 = H[(size_t)d0 * 32 + lane];
        float v0 = dot_reduce32(a, b0);
        if (lane == 0) out[seid[e]] = v0;
    }
}

// ---- fallback (R2 kernel) if ws too small ----
__global__ void edge_dot4_kernel(const float* __restrict__ h,
                                 const int* __restrict__ src,
                                 const int* __restrict__ dst,
                                 float* __restrict__ out, int n_edges) {
    const int lane = threadIdx.x & 31;
    const long long gid = ((long long)blockIdx.x * blockDim.x + threadIdx.x) >> 5;
    long long e0 = gid * 4;
    if (e0 >= n_edges) return;
    const float4* __restrict__ H = reinterpret_cast<const float4*>(h);
    for (long long e = e0; e < e0 + 4 && e < (long long)n_edges; ++e) {
        float4 a = H[(size_t)src[e] * 32 + lane];
        float4 b = H[(size_t)dst[e] * 32 + lane];
        float v = dot_reduce32(a, b);
        if (lane == 0) out[e] = v;
    }
}

extern "C" void kernel_launch(void* const* d_in, const int* in_sizes, int n_in,
                              void* d_out, int out_size, void* d_ws, size_t ws_size,
                              hipStream_t stream) {
    const float* h   = (const float*)d_in[0];
    const int*   src = (const int*)d_in[1];
    const int*   dst = (const int*)d_in[2];
    float*       out = (float*)d_out;

    const int N = in_sizes[0] / 128;   // 100000 nodes
    const int E = in_sizes[1];         // 600000 edges

    const int nScanBlocks = (N + SCAN_B - 1) / SCAN_B;   // 98

    // Workspace layout (u32 words)
    size_t need = ((size_t)3 * N + SCAN_B + 2 * (size_t)E) * 4 + 1024;
    if (ws_size < need || nScanBlocks > SCAN_B) {
        const int block = 256;
        long long n_groups = ((long long)E + 3) / 4;
        int grid = (int)((n_groups * 32 + block - 1) / block);
        edge_dot4_kernel<<<grid, block, 0, stream>>>(h, src, dst, out, E);
        return;
    }

    unsigned* cnt  = (unsigned*)d_ws;
    unsigned* cur  = cnt + N;
    unsigned* off  = cur + N;
    unsigned* part = off + N;
    unsigned* sdst = part + SCAN_B;
    unsigned* seid = sdst + E;

    hipMemsetAsync(cnt, 0, (size_t)N * 4, stream);
    hipMemsetAsync(cur, 0, (size_t)N * 4, stream);

    const int B = 256;
    k_hist<<<(E + B - 1) / B, B, 0, stream>>>(src, cnt, E);

    k_scan_block<<<nScanBlocks, SCAN_B, 0, stream>>>(cnt, off, part, N);
    k_scan_block<<<1, SCAN_B, 0, stream>>>(part, part, nullptr, nScanBlocks);
    k_scan_add<<<nScanBlocks, SCAN_B, 0, stream>>>(off, part, N);

    k_scatter<<<(E + B - 1) / B, B, 0, stream>>>(src, dst, off, cur, sdst, seid, E);

    long long n_threads = (long long)N * 32;
    k_node_dot<<<(int)((n_threads + B - 1) / B), B, 0, stream>>>(h, off, sdst, seid, out, N, E);
}

// Round 4
// 56.410 us; speedup vs baseline: 2.5435x; 2.5435x over previous
//
#include <hip/hip_runtime.h>

// score[e] = dot(h[src[e]], h[dst[e]]), D=128, E=600k, N=100k.
// R4: convert h to bf16 in d_ws (halves gathered bytes AND 128B-line count),
// then edge-parallel gather: 16 lanes/edge, 16B (8 bf16) per lane, f32 accum.

static __device__ __forceinline__ unsigned short f2bf(float x) {
    union { float f; unsigned u; } c; c.f = x;
    unsigned r = c.u + 0x7fffu + ((c.u >> 16) & 1u);   // round-to-nearest-even
    return (unsigned short)(r >> 16);
}
static __device__ __forceinline__ float bf_lo(unsigned u) {
    union { unsigned u; float f; } c; c.u = u << 16; return c.f;
}
static __device__ __forceinline__ float bf_hi(unsigned u) {
    union { unsigned u; float f; } c; c.u = u & 0xffff0000u; return c.f;
}

// h (f32) -> hb (bf16), 8 elems per thread.
__global__ void k_convert(const float* __restrict__ h, unsigned* __restrict__ hb,
                          long long n) {  // n = total f32 elems (multiple of 8)
    long long t = (long long)blockIdx.x * blockDim.x + threadIdx.x;
    long long i = t * 8;
    if (i >= n) return;
    const float4* H4 = reinterpret_cast<const float4*>(h);
    float4 v0 = H4[t * 2];
    float4 v1 = H4[t * 2 + 1];
    uint4 o;
    o.x = (unsigned)f2bf(v0.x) | ((unsigned)f2bf(v0.y) << 16);
    o.y = (unsigned)f2bf(v0.z) | ((unsigned)f2bf(v0.w) << 16);
    o.z = (unsigned)f2bf(v1.x) | ((unsigned)f2bf(v1.y) << 16);
    o.w = (unsigned)f2bf(v1.z) | ((unsigned)f2bf(v1.w) << 16);
    reinterpret_cast<uint4*>(hb)[t] = o;
}

// 16 lanes per edge; each lane: one uint4 (8 bf16) of src row + dst row.
__global__ void edge_dot_bf16(const unsigned* __restrict__ hb,
                              const int* __restrict__ src,
                              const int* __restrict__ dst,
                              float* __restrict__ out, int E) {
    const int lane = threadIdx.x & 15;
    long long g = ((long long)blockIdx.x * blockDim.x + threadIdx.x) >> 4;
    if (g >= E) return;

    const uint4* __restrict__ H = reinterpret_cast<const uint4*>(hb);  // row = 16 uint4
    size_t s = (size_t)src[g];
    size_t d = (size_t)dst[g];
    uint4 a = H[s * 16 + lane];
    uint4 b = H[d * 16 + lane];

    float v = 0.f;
    v = fmaf(bf_lo(a.x), bf_lo(b.x), v);
    v = fmaf(bf_hi(a.x), bf_hi(b.x), v);
    v = fmaf(bf_lo(a.y), bf_lo(b.y), v);
    v = fmaf(bf_hi(a.y), bf_hi(b.y), v);
    v = fmaf(bf_lo(a.z), bf_lo(b.z), v);
    v = fmaf(bf_hi(a.z), bf_hi(b.z), v);
    v = fmaf(bf_lo(a.w), bf_lo(b.w), v);
    v = fmaf(bf_hi(a.w), bf_hi(b.w), v);

    // reduce across the 16-lane group
    v += __shfl_xor(v, 8);
    v += __shfl_xor(v, 4);
    v += __shfl_xor(v, 2);
    v += __shfl_xor(v, 1);

    if (lane == 0) out[g] = v;
}

// ---- f32 fallback (R2 kernel) if workspace too small for bf16 copy ----
__device__ __forceinline__ float dot_reduce32(float4 a, float4 b) {
    float v = a.x * b.x + a.y * b.y + a.z * b.z + a.w * b.w;
    v += __shfl_xor(v, 16);
    v += __shfl_xor(v, 8);
    v += __shfl_xor(v, 4);
    v += __shfl_xor(v, 2);
    v += __shfl_xor(v, 1);
    return v;
}
__global__ void edge_dot_f32(const float* __restrict__ h,
                             const int* __restrict__ src,
                             const int* __restrict__ dst,
                             float* __restrict__ out, int E) {
    const int lane = threadIdx.x & 31;
    long long g = ((long long)blockIdx.x * blockDim.x + threadIdx.x) >> 5;
    if (g >= E) return;
    const float4* __restrict__ H = reinterpret_cast<const float4*>(h);
    float4 a = H[(size_t)src[g] * 32 + lane];
    float4 b = H[(size_t)dst[g] * 32 + lane];
    float v = dot_reduce32(a, b);
    if (lane == 0) out[g] = v;
}

extern "C" void kernel_launch(void* const* d_in, const int* in_sizes, int n_in,
                              void* d_out, int out_size, void* d_ws, size_t ws_size,
                              hipStream_t stream) {
    const float* h   = (const float*)d_in[0];
    const int*   src = (const int*)d_in[1];
    const int*   dst = (const int*)d_in[2];
    float*       out = (float*)d_out;

    const long long nElem = in_sizes[0];   // N * 128 = 12.8M
    const int E = in_sizes[1];             // 600000

    const int B = 256;
    size_t need = (size_t)nElem * 2;       // bf16 copy of h

    if (ws_size >= need) {
        unsigned* hb = (unsigned*)d_ws;
        long long nThreadsConv = nElem / 8;
        int gridConv = (int)((nThreadsConv + B - 1) / B);
        k_convert<<<gridConv, B, 0, stream>>>(h, hb, nElem);

        long long nThreads = (long long)E * 16;
        int grid = (int)((nThreads + B - 1) / B);
        edge_dot_bf16<<<grid, B, 0, stream>>>(hb, src, dst, out, E);
    } else {
        long long nThreads = (long long)E * 32;
        int grid = (int)((nThreads + B - 1) / B);
        edge_dot_f32<<<grid, B, 0, stream>>>(h, src, dst, out, E);
    }
}